// Round 12
// baseline (1264.273 us; speedup 1.0000x reference)
//
#include <hip/hip_runtime.h>
#include <hip/hip_cooperative_groups.h>

namespace cg = cooperative_groups;

// ---------------- constants (problem shape) ----------------
#define NL 2
#define DMODEL 256
#define DI 512
#define FF 1024
#define LSEQ 1024
#define NN 16
#define KCONV 4
#define BTOK 2048   // B * LSEQ
#define EPS 1e-5f

using short8 = __attribute__((ext_vector_type(8))) short;
using float4v = __attribute__((ext_vector_type(4))) float;
typedef unsigned short u16;

__device__ inline float bf2f(u16 u) {
    union { unsigned u; float f; } x; x.u = (unsigned)u << 16; return x.f;
}
__device__ inline u16 f2bf(float f) {
    union { float f; unsigned u; } x; x.f = f;
    unsigned r = x.u + 0x7fffu + ((x.u >> 16) & 1u);
    return (u16)(r >> 16);
}

#if __has_builtin(__builtin_amdgcn_exp2f)
#define EXP2(x) __builtin_amdgcn_exp2f(x)
#else
#define EXP2(x) exp2f(x)
#endif

// ---------------- arg bundle ----------------
struct TMat { const float* src; u16* dst; int rows, cols, tile0, tilecols; };
struct TTable { TMat m[24]; int nmat; };

struct MegaArgs {
    TTable tt; int ttiles;
    const int* ids;
    const float *emb, *pos, *conv_w, *conv_b, *A_log, *Dskip, *bdt;
    const float *bn_g, *bn_b, *ln_g, *ln_b, *ff_b1, *ff_b2, *bout, *final_b;
    const u16 *winT, *wxT, *wdtT, *woutT, *fw1T, *fw2T, *finT;
    u16 *xbuf, *xz, *xc, *bcT, *deltaT, *uT, *pT, *ybuf, *outm, *ffin, *ffh, *ffo;
    float *statsM, *statsF;
    float* dout;
};

// ---------------- phase: weight transpose (fp32 -> bf16, N-major) ----------------
__device__ void transpose_phase(const TTable& tt, int ttiles, char* smem_) {
    u16 (*tile)[33] = (u16(*)[33])smem_;
    int tx = threadIdx.x & 31, ty = threadIdx.x >> 5;
    for (int bx = blockIdx.x; bx < ttiles; bx += gridDim.x) {
        __syncthreads();
        int j = 0;
        for (int k = 1; k < tt.nmat; ++k) if (bx >= tt.m[k].tile0) j = k;
        TMat mm = tt.m[j];
        int lt = bx - mm.tile0;
        int r0 = (lt / mm.tilecols) * 32, c0 = (lt % mm.tilecols) * 32;
        #pragma unroll
        for (int k = 0; k < 4; ++k) {
            int r = r0 + ty + k * 8, c = c0 + tx;
            tile[ty + k * 8][tx] = (r < mm.rows && c < mm.cols) ? f2bf(mm.src[(size_t)r * mm.cols + c]) : (u16)0;
        }
        __syncthreads();
        #pragma unroll
        for (int k = 0; k < 4; ++k) {
            int c = c0 + ty + k * 8, r = r0 + tx;
            if (c < mm.cols && r < mm.rows) mm.dst[(size_t)c * mm.rows + r] = tile[tx][ty + k * 8];
        }
    }
}

// ---------------- phase: embedding ----------------
__device__ void embed_phase(const int* ids, const float* emb, const float* pos, u16* x) {
    int d = threadIdx.x;
    for (int tok = blockIdx.x; tok < BTOK; tok += gridDim.x) {
        int id = ids[tok];
        float v = emb[(size_t)id * DMODEL + d] * 16.0f + pos[(size_t)(tok & (LSEQ - 1)) * DMODEL + d];
        x[(size_t)tok * DMODEL + d] = f2bf(v);
    }
}

// ---------------- phase: LDS-staged MFMA GEMM (+ optional channel stats) ----------------
template<int BM, int BN, int WR, int WC, int RT, int CT>
__device__ void sgemm_phase(
    const u16* A0, int lda, unsigned long long sA,
    const u16* B0, int ldb, unsigned long long sB,
    const float* bias0, unsigned long long sBias,
    void* C0, int ldc, unsigned long long sC,
    int K, int act, int outfp, float* stats, int statsStride,
    int nbx, int nby, int nbz, char* smem_)
{
    constexpr int BK = 32;
    u16* As = (u16*)smem_;
    u16* Bs = As + BM * BK;
    const int tid = threadIdx.x, w = tid >> 6, lane = tid & 63;
    const int wr = w / WC, wc = w % WC;
    const int mi = lane & 15, kq = lane >> 4;
    const int lr = lane >> 2, lc = (lane & 3) * 8;
    const int ntiles = nbx * nby * nbz;
    for (int vb = blockIdx.x; vb < ntiles; vb += gridDim.x) {
        int bz = vb / (nbx * nby);
        int rem = vb - bz * (nbx * nby);
        int by = rem / nbx, bx = rem - by * nbx;
        const u16* A = A0 + (size_t)bz * sA;
        const u16* Bt = B0 + (size_t)bz * sB;
        const float* bias = bias0 ? (bias0 + (size_t)bz * sBias) : nullptr;
        const int row0 = by * BM, col0 = bx * BN;

        float4v acc[RT][CT];
        #pragma unroll
        for (int i = 0; i < RT; ++i)
            #pragma unroll
            for (int j = 0; j < CT; ++j) acc[i][j] = (float4v){0.f, 0.f, 0.f, 0.f};

        for (int kk = 0; kk < K; kk += BK) {
            __syncthreads();
            for (int i = w; i < BM / 16; i += 4) {
                const u16* g = A + (size_t)(row0 + i * 16 + lr) * lda + kk + lc;
                __builtin_amdgcn_global_load_lds(
                    (const __attribute__((address_space(1))) void*)g,
                    (__attribute__((address_space(3))) void*)(As + i * 16 * BK), 16, 0, 0);
            }
            for (int i = w; i < BN / 16; i += 4) {
                const u16* g = Bt + (size_t)(col0 + i * 16 + lr) * ldb + kk + lc;
                __builtin_amdgcn_global_load_lds(
                    (const __attribute__((address_space(1))) void*)g,
                    (__attribute__((address_space(3))) void*)(Bs + i * 16 * BK), 16, 0, 0);
            }
            __syncthreads();
            short8 af[RT], bf[CT];
            #pragma unroll
            for (int i = 0; i < RT; ++i)
                af[i] = *(const short8*)(As + (wr * RT * 16 + i * 16 + mi) * BK + kq * 8);
            #pragma unroll
            for (int j = 0; j < CT; ++j)
                bf[j] = *(const short8*)(Bs + (wc * CT * 16 + j * 16 + mi) * BK + kq * 8);
            #pragma unroll
            for (int i = 0; i < RT; ++i)
                #pragma unroll
                for (int j = 0; j < CT; ++j)
                    acc[i][j] = __builtin_amdgcn_mfma_f32_16x16x32_bf16(af[i], bf[j], acc[i][j], 0, 0, 0);
        }

        #pragma unroll
        for (int j = 0; j < CT; ++j) {
            const int n = col0 + wc * CT * 16 + j * 16 + mi;
            const float bv = bias ? bias[n] : 0.f;
            float s = 0.f, q = 0.f;
            #pragma unroll
            for (int i = 0; i < RT; ++i) {
                #pragma unroll
                for (int r = 0; r < 4; ++r) {
                    int m = row0 + wr * RT * 16 + i * 16 + kq * 4 + r;
                    float v = acc[i][j][r] + bv;
                    if (act == 1) v = fmaxf(v, 0.f);
                    if (outfp)
                        ((float*)C0)[(size_t)bz * sC + (size_t)m * ldc + n] = v;
                    else
                        ((u16*)C0)[(size_t)bz * sC + (size_t)m * ldc + n] = f2bf(v);
                    s += v; q += v * v;
                }
            }
            if (stats) {
                s += __shfl_xor(s, 16); s += __shfl_xor(s, 32);
                q += __shfl_xor(q, 16); q += __shfl_xor(q, 32);
                if (lane < 16) {
                    atomicAdd(&stats[(size_t)(bz * statsStride + n) * 2], s);
                    atomicAdd(&stats[(size_t)(bz * statsStride + n) * 2 + 1], q);
                }
            }
        }
    }
}

// ---------------- phase: depthwise conv + SiLU ----------------
__device__ void conv_phase(const u16* xz, const float* conv_w, const float* conv_b,
                           u16* xc, int layer) {
    for (int vb = blockIdx.x; vb < 8192; vb += gridDim.x) {
        unsigned g = vb * 256u + threadIdx.x;
        int d = g & 511;
        int t = (g >> 9) & 1023;
        int b = (g >> 19) & 1;
        int dir = g >> 20;
        int wbase = ((layer * 2 + dir) * DI + d);
        float acc = conv_b[wbase];
        int colbase = dir * 1024 + d;
        #pragma unroll
        for (int k = 0; k < KCONV; ++k) {
            int ts = dir ? (t + 3 - k) : (t - 3 + k);
            if (ts >= 0 && ts < LSEQ)
                acc += conv_w[wbase * KCONV + k] * bf2f(xz[(size_t)((b << 10) + ts) * 2048 + colbase]);
        }
        float v = acc / (1.f + __expf(-acc));
        xc[(size_t)(((dir * 2 + b) << 10) + t) * DI + d] = f2bf(v);
    }
}

// ---------------- phase: xdb GEMM (N=48) + bcT write + delta GEMM fused in-block ----
// virtual blocks: 512 = dir(2) x tile(128 of 16 tokens) x half(2).
__device__ void xdb_delta_phase(const u16* xc, const u16* wxT_l, const u16* wdtT_l,
                                const float* bdt_l, u16* bcT, u16* deltaT, u16* uT,
                                char* smem_) {
    u16* xdb16 = (u16*)smem_;   // [16][16]
    const short8 zer = {0, 0, 0, 0, 0, 0, 0, 0};
    int w = threadIdx.x >> 6, lane = threadIdx.x & 63;
    int mi = lane & 15, kq = lane >> 4;
    for (int vb = blockIdx.x; vb < 512; vb += gridDim.x) {
        __syncthreads();
        int dir = vb >> 8, r5 = vb & 255, tile = r5 >> 1, half = r5 & 1;
        int m0 = tile * 16;
        int b = m0 >> 10, tbase = m0 & 1023;
        // ---- xdb tile (16 x 48), waves 0..2 own col tile w ----
        if (w < 3) {
            int n = w * 16 + mi;
            const u16* Arow = xc + ((size_t)(dir * BTOK + m0 + mi)) * 512;
            const u16* Brow = wxT_l + (size_t)dir * 48 * 512 + (size_t)n * 512;
            float4v acc = (float4v){0.f, 0.f, 0.f, 0.f};
            for (int kk = 0; kk < 512; kk += 32) {
                short8 af = *(const short8*)(Arow + kk + kq * 8);
                short8 bf = *(const short8*)(Brow + kk + kq * 8);
                acc = __builtin_amdgcn_mfma_f32_16x16x32_bf16(af, bf, acc, 0, 0, 0);
            }
            #pragma unroll
            for (int rr = 0; rr < 4; ++rr) {
                int m = kq * 4 + rr;
                u16 hv = f2bf(acc[rr]);
                if (w == 0) xdb16[m * 16 + mi] = hv;
                else if ((half == 0 && w == 1) || (half == 1 && w == 2))
                    bcT[((size_t)((dir * 2 + b) * 32 + (n - 16))) * 1024 + tbase + m] = hv;
            }
        }
        __syncthreads();
        // ---- delta tile (16 x 256 per half), K=16 from LDS ----
        short8 af = (kq < 2) ? *(const short8*)(xdb16 + mi * 16 + kq * 8) : zer;
        const u16* wdtTd = wdtT_l + (size_t)dir * 512 * 16;
        const float* biasd = bdt_l + (size_t)dir * 512;
        #pragma unroll
        for (int ct = 0; ct < 4; ++ct) {
            int n = half * 256 + w * 64 + ct * 16 + mi;
            short8 bf = (kq < 2) ? *(const short8*)(wdtTd + (size_t)n * 16 + kq * 8) : zer;
            float4v acc = __builtin_amdgcn_mfma_f32_16x16x32_bf16(af, bf,
                          (float4v){0.f, 0.f, 0.f, 0.f}, 0, 0, 0);
            #pragma unroll
            for (int rr = 0; rr < 4; ++rr) {
                int m = kq * 4 + rr;
                float v = acc[rr] + biasd[n];
                v = (v > 20.f) ? v : logf(1.f + __expf(v));   // softplus
                float xcv = bf2f(xc[((size_t)(dir * BTOK + m0 + m)) * 512 + n]);
                size_t off = ((size_t)((dir * 2 + b) * 512 + n)) * 1024 + tbase + m;
                deltaT[off] = f2bf(v);
                uT[off] = f2bf(v * xcv);
            }
        }
    }
}

// ---------------- phase: selective scan (n-outer streaming + K-S stitch) ----------------
template<int DIR>
__device__ void scan_body(int c, int d, int slab,
    const u16* __restrict__ deltaT, const u16* __restrict__ uT,
    const u16* __restrict__ bcT, const float* __restrict__ A_log,
    u16* __restrict__ pT, int layer, float* Ps, float* Qs)
{
    float a2[16];
    const float* al = A_log + (size_t)(((layer * 2 + DIR) * DI + d) * NN);
    #pragma unroll
    for (int n = 0; n < 16; ++n) a2[n] = -__expf(al[n]) * 1.44269504f;

    const size_t tb = ((size_t)(slab * DI + d)) * LSEQ;
    const size_t bcb = (size_t)slab * 32 * LSEQ;
    const int T0 = DIR ? (1016 - 8 * c) : (8 * c);

    short8 dlv = *(const short8*)(deltaT + tb + T0);
    short8 uvv = *(const short8*)(uT + tb + T0);
    float dls[8], uvs[8];
    #pragma unroll
    for (int s = 0; s < 8; ++s) {
        const int idx = DIR ? 7 - s : s;
        dls[s] = bf2f((u16)dlv[idx]);
        uvs[s] = bf2f((u16)uvv[idx]);
    }

    const int base = c * 17;
    #pragma unroll
    for (int n = 0; n < 16; ++n) {
        short8 B8 = *(const short8*)(bcT + bcb + (size_t)n * LSEQ + T0);
        float P = 1.f, Q = 0.f;
        #pragma unroll
        for (int s = 0; s < 8; ++s) {
            const int idx = DIR ? 7 - s : s;
            float dA = EXP2(dls[s] * a2[n]);
            Q = Q * dA + uvs[s] * bf2f((u16)B8[idx]);
            P *= dA;
        }
        Ps[base + n] = P;
        Qs[base + n] = Q;
    }
    __syncthreads();

    for (int off = 1; off < 128; off <<= 1) {
        float np[16], nq[16];
        const bool act = (c >= off);
        if (act) {
            const int nb = (c - off) * 17;
            #pragma unroll
            for (int n = 0; n < 16; ++n) { np[n] = Ps[nb + n]; nq[n] = Qs[nb + n]; }
        }
        __syncthreads();
        if (act) {
            #pragma unroll
            for (int n = 0; n < 16; ++n) {
                float p = Ps[base + n], q = Qs[base + n];
                Qs[base + n] = fmaf(p, nq[n], q);
                Ps[base + n] = p * np[n];
            }
        }
        __syncthreads();
    }

    float pacc[8];
    #pragma unroll
    for (int s = 0; s < 8; ++s) pacc[s] = 0.f;
    const int hb = (c - 1) * 17;
    #pragma unroll
    for (int n = 0; n < 16; ++n) {
        short8 B8 = *(const short8*)(bcT + bcb + (size_t)n * LSEQ + T0);
        short8 C8 = *(const short8*)(bcT + bcb + (size_t)(16 + n) * LSEQ + T0);
        float h = (c == 0) ? 0.f : Qs[hb + n];
        #pragma unroll
        for (int s = 0; s < 8; ++s) {
            const int idx = DIR ? 7 - s : s;
            float dA = EXP2(dls[s] * a2[n]);
            h = h * dA + uvs[s] * bf2f((u16)B8[idx]);
            pacc[s] = fmaf(h, bf2f((u16)C8[idx]), pacc[s]);
        }
    }
    short8 pk;
    #pragma unroll
    for (int s = 0; s < 8; ++s) {
        const int idx = DIR ? 7 - s : s;
        pk[idx] = (short)f2bf(pacc[s]);
    }
    *(short8*)(pT + tb + T0) = pk;
}

__device__ void scan_phase(const u16* deltaT, const u16* uT, const u16* bcT,
                           const float* A_log, u16* pT, int layer, char* smem_) {
    float* sf = (float*)smem_;
    int half = threadIdx.x >> 7;
    int c = threadIdx.x & 127;
    float* Ps = sf + half * 4352;
    float* Qs = Ps + 2176;
    // NOTE: pairs (2vb, 2vb+1) always share a slab (slab boundaries are even),
    // so both halves take the same DIR branch -> barrier counts match.
    for (int vb = blockIdx.x; vb < 1024; vb += gridDim.x) {
        __syncthreads();
        int pair = vb * 2 + half;
        int slab = pair >> 9, d = pair & 511;
        if (slab >> 1)
            scan_body<1>(c, d, slab, deltaT, uT, bcT, A_log, pT, layer, Ps, Qs);
        else
            scan_body<0>(c, d, slab, deltaT, uT, bcT, A_log, pT, layer, Ps, Qs);
    }
}

// ---------------- phase: gate (pT -> token-major, skip + silu(z)); zero statsM ------
__device__ void gate_phase(const u16* pT, const u16* xc, const u16* xz,
                           const float* Dskip, u16* y, float* statsM, int layer,
                           char* smem_) {
    if (blockIdx.x == 0)
        for (int k = threadIdx.x; k < 2048; k += 256) statsM[k] = 0.f;
    float (*tile)[33] = (float(*)[33])smem_;
    int tx = threadIdx.x & 31, ty = threadIdx.x >> 5;
    for (int vb = blockIdx.x; vb < 2048; vb += gridDim.x) {
        __syncthreads();
        int z = vb >> 9, rem = vb & 511;
        int t0 = (rem >> 4) * 32, d0 = (rem & 15) * 32;
        int dir = z >> 1, b = z & 1;
        #pragma unroll
        for (int k = 0; k < 4; ++k) {
            int d = d0 + ty + k * 8;
            tile[ty + k * 8][tx] = bf2f(pT[((size_t)(z * DI + d)) * LSEQ + t0 + tx]);
        }
        __syncthreads();
        #pragma unroll
        for (int k = 0; k < 4; ++k) {
            int t = t0 + ty + k * 8, d = d0 + tx;
            float p = tile[tx][ty + k * 8];
            float xcv = bf2f(xc[(size_t)((z << 10) + t) * DI + d]);
            float zv = bf2f(xz[(size_t)((b << 10) + t) * 2048 + dir * 1024 + 512 + d]);
            float dsk = Dskip[(layer * 2 + dir) * DI + d];
            float yv = (p + dsk * xcv) * (zv / (1.f + __expf(-zv)));
            y[(size_t)((z << 10) + t) * DI + d] = f2bf(yv);
        }
    }
}

// ------- phase: BN-apply(from raw sums) + residual + LN both + sum; zero statsF ------
__device__ void fuseln_phase(const u16* x, const u16* outm, const float* stats,
                             const float* bng, const float* bnb,
                             const float* lng, const float* lnb,
                             u16* ffin, float* statsF, char* smem_) {
    if (blockIdx.x == 0)
        for (int k = threadIdx.x; k < 512; k += 256) statsF[k] = 0.f;
    float* sm = (float*)smem_;   // [4][4]
    int d = threadIdx.x;
    float mf0 = stats[d * 2] * (1.f / 2048.f);
    float rf0 = rsqrtf(stats[d * 2 + 1] * (1.f / 2048.f) - mf0 * mf0 + EPS);
    float mb0 = stats[(DMODEL + d) * 2] * (1.f / 2048.f);
    float rb0 = rsqrtf(stats[(DMODEL + d) * 2 + 1] * (1.f / 2048.f) - mb0 * mb0 + EPS);
    float gf = bng[d], gb = bng[DMODEL + d], bf_ = bnb[d], bb_ = bnb[DMODEL + d];
    float lgf = lng[d], lgb = lng[DMODEL + d], lbf = lnb[d], lbb = lnb[DMODEL + d];
    for (int tok = blockIdx.x; tok < BTOK; tok += gridDim.x) {
        __syncthreads();
        float xv = bf2f(x[(size_t)tok * DMODEL + d]);
        float of = bf2f(outm[(size_t)tok * DMODEL + d]);
        float ob = bf2f(outm[(size_t)BTOK * DMODEL + (size_t)tok * DMODEL + d]);
        float vf = xv + (of - mf0) * rf0 * gf + bf_;
        float vb = xv + (ob - mb0) * rb0 * gb + bb_;
        float s0 = vf, s1 = vf * vf, s2 = vb, s3 = vb * vb;
        #pragma unroll
        for (int off = 1; off < 64; off <<= 1) {
            s0 += __shfl_xor(s0, off); s1 += __shfl_xor(s1, off);
            s2 += __shfl_xor(s2, off); s3 += __shfl_xor(s3, off);
        }
        if ((d & 63) == 0) {
            sm[(d >> 6) * 4] = s0; sm[(d >> 6) * 4 + 1] = s1;
            sm[(d >> 6) * 4 + 2] = s2; sm[(d >> 6) * 4 + 3] = s3;
        }
        __syncthreads();
        s0 = sm[0] + sm[4] + sm[8] + sm[12];
        s1 = sm[1] + sm[5] + sm[9] + sm[13];
        s2 = sm[2] + sm[6] + sm[10] + sm[14];
        s3 = sm[3] + sm[7] + sm[11] + sm[15];
        float mf = s0 * (1.f / 256.f), vvf = s1 * (1.f / 256.f) - mf * mf;
        float mb = s2 * (1.f / 256.f), vvb = s3 * (1.f / 256.f) - mb * mb;
        float fl = (vf - mf) * rsqrtf(vvf + EPS) * lgf + lbf;
        float bl = (vb - mb) * rsqrtf(vvb + EPS) * lgb + lbb;
        ffin[(size_t)tok * DMODEL + d] = f2bf(fl + bl);
    }
}

// ---------------- phase: BN-apply(ff) + residual add into x ----------------
__device__ void bnadd_phase(u16* x, const u16* ffo, const float* stats,
                            const float* g, const float* b) {
    int d = threadIdx.x;
    float mean = stats[d * 2] * (1.f / 2048.f);
    float rs = rsqrtf(stats[d * 2 + 1] * (1.f / 2048.f) - mean * mean + EPS);
    float gv = g[d], bv = b[d];
    for (int tok = blockIdx.x; tok < BTOK; tok += gridDim.x) {
        size_t idx = (size_t)tok * DMODEL + d;
        float v = bf2f(x[idx]) + (bf2f(ffo[idx]) - mean) * rs * gv + bv;
        x[idx] = f2bf(v);
    }
}

// ---------------- the mega kernel ----------------
// __launch_bounds__(256, 2): cap VGPR at 256 so >= 2 blocks/CU are co-resident
// (512-block cooperative launch needs 2/CU; r11 without this hit the
// cooperative-launch-too-large rejection and never ran).
__global__ __launch_bounds__(256, 2) void mega_kernel(MegaArgs a) {
    cg::grid_group gg = cg::this_grid();
    __shared__ alignas(16) char smem[34816];

    transpose_phase(a.tt, a.ttiles, smem);
    embed_phase(a.ids, a.emb, a.pos, a.xbuf);
    gg.sync();

    for (int i = 0; i < NL; ++i) {
        // xz = x @ [Win_f | Win_b]
        sgemm_phase<128, 64, 4, 1, 2, 4>(a.xbuf, 256, 0ULL,
            a.winT + (size_t)i * 2048 * 256, 256, 0ULL, nullptr, 0ULL,
            a.xz, 2048, 0ULL, 256, 0, 0, nullptr, 0, 32, 16, 1, smem);
        gg.sync();
        conv_phase(a.xz, a.conv_w, a.conv_b, a.xc, i);
        gg.sync();
        xdb_delta_phase(a.xc, a.wxT + (size_t)i * 2 * 48 * 512,
            a.wdtT + (size_t)i * 2 * 512 * 16, a.bdt + (size_t)i * 2 * 512,
            a.bcT, a.deltaT, a.uT, smem);
        gg.sync();
        scan_phase(a.deltaT, a.uT, a.bcT, a.A_log, a.pT, i, smem);
        gg.sync();
        gate_phase(a.pT, a.xc, a.xz, a.Dskip, a.ybuf, a.statsM, i, smem);
        gg.sync();
        // out_m = y @ Wout + bout (batched over dir) + channel stats
        sgemm_phase<64, 64, 2, 2, 2, 2>(a.ybuf, 512, (unsigned long long)BTOK * 512,
            a.woutT + (size_t)i * 2 * 256 * 512, 512, 256ULL * 512,
            a.bout + (size_t)i * 2 * 256, 256ULL,
            a.outm, 256, (unsigned long long)BTOK * 256, 512, 0, 0,
            a.statsM, 256, 4, 32, 2, smem);
        gg.sync();
        fuseln_phase(a.xbuf, a.outm, a.statsM,
            a.bn_g + (size_t)i * 3 * 256, a.bn_b + (size_t)i * 3 * 256,
            a.ln_g + (size_t)i * 2 * 256, a.ln_b + (size_t)i * 2 * 256,
            a.ffin, a.statsF, smem);
        gg.sync();
        sgemm_phase<64, 64, 2, 2, 2, 2>(a.ffin, 256, 0ULL,
            a.fw1T + (size_t)i * 1024 * 256, 256, 0ULL,
            a.ff_b1 + (size_t)i * 1024, 0ULL,
            a.ffh, 1024, 0ULL, 256, 1, 0, nullptr, 0, 16, 32, 1, smem);
        gg.sync();
        sgemm_phase<32, 64, 2, 2, 1, 2>(a.ffh, 1024, 0ULL,
            a.fw2T + (size_t)i * 256 * 1024, 1024, 0ULL,
            a.ff_b2 + (size_t)i * 256, 0ULL,
            a.ffo, 256, 0ULL, 1024, 0, 0, a.statsF, 0, 4, 64, 1, smem);
        gg.sync();
        bnadd_phase(a.xbuf, a.ffo, a.statsF,
            a.bn_g + (size_t)(i * 3 + 2) * 256, a.bn_b + (size_t)(i * 3 + 2) * 256);
        gg.sync();
    }
    // final logits (fp32 out)
    sgemm_phase<64, 64, 2, 2, 2, 2>(a.xbuf, 256, 0ULL, a.finT, 256, 0ULL,
        a.final_b, 0ULL, a.dout, 1024, 0ULL, 256, 0, 1, nullptr, 0, 16, 32, 1, smem);
}

// ---------------- host ----------------
extern "C" void kernel_launch(void* const* d_in, const int* in_sizes, int n_in,
                              void* d_out, int out_size, void* d_ws, size_t ws_size,
                              hipStream_t stream)
{
    MegaArgs a;
    a.ids     = (const int*)d_in[0];
    a.emb     = (const float*)d_in[1];
    a.pos     = (const float*)d_in[2];
    const float* Win    = (const float*)d_in[3];
    a.conv_w  = (const float*)d_in[4];
    a.conv_b  = (const float*)d_in[5];
    const float* Wx     = (const float*)d_in[6];
    const float* Wdt    = (const float*)d_in[7];
    a.bdt     = (const float*)d_in[8];
    a.A_log   = (const float*)d_in[9];
    a.Dskip   = (const float*)d_in[10];
    const float* Wout   = (const float*)d_in[11];
    a.bout    = (const float*)d_in[12];
    a.bn_g    = (const float*)d_in[13];
    a.bn_b    = (const float*)d_in[14];
    a.ln_g    = (const float*)d_in[15];
    a.ln_b    = (const float*)d_in[16];
    const float* ff_w1  = (const float*)d_in[17];
    a.ff_b1   = (const float*)d_in[18];
    const float* ff_w2  = (const float*)d_in[19];
    a.ff_b2   = (const float*)d_in[20];
    const float* final_w = (const float*)d_in[21];
    a.final_b = (const float*)d_in[22];
    a.dout    = (float*)d_out;

    char* cur = (char*)d_ws;
    auto alloc = [&](size_t elems) {
        u16* p = (u16*)cur;
        cur += ((elems * 2 + 511) / 512) * 512;
        return p;
    };
    u16* winT  = alloc((size_t)NL * 2048 * 256);
    u16* wxT   = alloc((size_t)NL * 2 * 48 * 512);
    u16* wdtT  = alloc((size_t)NL * 2 * 512 * 16);
    u16* woutT = alloc((size_t)NL * 2 * 256 * 512);
    u16* fw1T  = alloc((size_t)NL * 1024 * 256);
    u16* fw2T  = alloc((size_t)NL * 256 * 1024);
    u16* finT  = alloc((size_t)1024 * 256);
    a.winT = winT; a.wxT = wxT; a.wdtT = wdtT; a.woutT = woutT;
    a.fw1T = fw1T; a.fw2T = fw2T; a.finT = finT;
    a.xbuf   = alloc((size_t)BTOK * DMODEL);
    a.xz     = alloc((size_t)BTOK * 2048);
    a.xc     = alloc((size_t)2 * BTOK * DI);
    a.bcT    = alloc((size_t)4 * 32 * LSEQ);
    a.deltaT = alloc((size_t)2 * BTOK * DI);
    a.uT     = alloc((size_t)2 * BTOK * DI);
    a.pT     = alloc((size_t)2 * BTOK * DI);
    a.ybuf   = alloc((size_t)2 * BTOK * DI);
    a.outm   = alloc((size_t)2 * BTOK * DMODEL);
    a.ffin   = alloc((size_t)BTOK * DMODEL);
    a.ffh    = alloc((size_t)BTOK * FF);
    a.ffo    = alloc((size_t)BTOK * DMODEL);
    a.statsM = (float*)alloc(8192);               // 16KB: 1024+256 (sum,sumsq) pairs w/ slack
    a.statsF = a.statsM + 2048;

    // ---- build transpose table ----
    int nm = 0, tiles = 0;
    auto addT = [&](const float* src, u16* dst, int rows, int cols) {
        int tc = (cols + 31) / 32, tr = (rows + 31) / 32;
        a.tt.m[nm] = {src, dst, rows, cols, tiles, tc};
        tiles += tc * tr; nm++;
    };
    for (int i = 0; i < NL; ++i) {
        for (int dir = 0; dir < 2; ++dir) {
            addT(Win  + (size_t)(i * 2 + dir) * 256 * 1024, winT  + (size_t)i * 2048 * 256 + (size_t)dir * 1024 * 256, 256, 1024);
            addT(Wx   + (size_t)(i * 2 + dir) * 512 * 48,   wxT   + (size_t)(i * 2 + dir) * 48 * 512,   512, 48);
            addT(Wdt  + (size_t)(i * 2 + dir) * 16 * 512,   wdtT  + (size_t)(i * 2 + dir) * 512 * 16,   16, 512);
            addT(Wout + (size_t)(i * 2 + dir) * 512 * 256,  woutT + (size_t)(i * 2 + dir) * 256 * 512,  512, 256);
        }
        addT(ff_w1 + (size_t)i * 256 * 1024, fw1T + (size_t)i * 1024 * 256, 256, 1024);
        addT(ff_w2 + (size_t)i * 1024 * 256, fw2T + (size_t)i * 256 * 1024, 1024, 256);
    }
    addT(final_w, finT, 256, 1024);
    a.tt.nmat = nm;
    a.ttiles = tiles;

    // Clamp grid to guaranteed co-residency (pure queries; graph-capture safe).
    int dev = 0;
    hipGetDevice(&dev);
    int nb = 0, cus = 0;
    hipOccupancyMaxActiveBlocksPerMultiprocessor(&nb, (const void*)mega_kernel, 256, 0);
    hipDeviceGetAttribute(&cus, hipDeviceAttributeMultiprocessorCount, dev);
    int grid = 512;
    if (nb > 0 && cus > 0 && nb * cus < grid) grid = nb * cus;

    void* kargs[1] = { &a };
    hipLaunchCooperativeKernel((void*)mega_kernel, dim3(grid), dim3(256),
                               kargs, 0, stream);
}

// Round 13
// 393.228 us; speedup vs baseline: 3.2151x; 3.2151x over previous
//
#include <hip/hip_runtime.h>

// ---------------- constants (problem shape) ----------------
#define NL 2
#define DMODEL 256
#define DI 512
#define FF 1024
#define LSEQ 1024
#define NN 16
#define KCONV 4
#define BTOK 2048   // B * LSEQ
#define EPS 1e-5f
#define XCP 520     // padded LDS row (16B-aligned, breaks 16-way bank conflict)

using short8 = __attribute__((ext_vector_type(8))) short;
using float4v = __attribute__((ext_vector_type(4))) float;
typedef unsigned short u16;

__device__ inline float bf2f(u16 u) {
    union { unsigned u; float f; } x; x.u = (unsigned)u << 16; return x.f;
}
__device__ inline u16 f2bf(float f) {
    union { float f; unsigned u; } x; x.f = f;
    unsigned r = x.u + 0x7fffu + ((x.u >> 16) & 1u);
    return (u16)(r >> 16);
}

#if __has_builtin(__builtin_amdgcn_exp2f)
#define EXP2(x) __builtin_amdgcn_exp2f(x)
#else
#define EXP2(x) exp2f(x)
#endif

// ---------------- transpose-all (fp32 weights -> bf16 N-major B^T) ----------------
struct TMat { const float* src; u16* dst; int rows, cols, tile0, tilecols; };
struct TTable { TMat m[24]; int nmat; };

__global__ __launch_bounds__(256) void transpose_kernel(TTable tt) {
    __shared__ u16 tile[32][33];
    int bx = blockIdx.x;
    int j = 0;
    for (int k = 1; k < tt.nmat; ++k) if (bx >= tt.m[k].tile0) j = k;
    TMat mm = tt.m[j];
    int lt = bx - mm.tile0;
    int r0 = (lt / mm.tilecols) * 32, c0 = (lt % mm.tilecols) * 32;
    int tx = threadIdx.x & 31, ty = threadIdx.x >> 5;
    #pragma unroll
    for (int k = 0; k < 4; ++k) {
        int r = r0 + ty + k * 8, c = c0 + tx;
        tile[ty + k * 8][tx] = (r < mm.rows && c < mm.cols) ? f2bf(mm.src[(size_t)r * mm.cols + c]) : (u16)0;
    }
    __syncthreads();
    #pragma unroll
    for (int k = 0; k < 4; ++k) {
        int c = c0 + ty + k * 8, r = r0 + tx;
        if (c < mm.cols && r < mm.rows) mm.dst[(size_t)c * mm.rows + r] = tile[tx][ty + k * 8];
    }
}

// ---------------- LDS-staged MFMA GEMM: C = act(A @ Bt^T + bias) [+ channel stats] ---
template<int BM, int BN, int WR, int WC, int RT, int CT>
__global__ __launch_bounds__(256) void sgemm_kernel(
    const u16* __restrict__ A0, int lda, unsigned long long sA,
    const u16* __restrict__ B0, int ldb, unsigned long long sB,
    const float* __restrict__ bias0, unsigned long long sBias,
    void* __restrict__ C0, int ldc, unsigned long long sC,
    int K, int act, int outfp, float* __restrict__ stats, int statsStride)
{
    constexpr int BK = 32;
    __shared__ u16 As[BM * BK];
    __shared__ u16 Bs[BN * BK];
    const u16* A = A0 + (size_t)blockIdx.z * sA;
    const u16* Bt = B0 + (size_t)blockIdx.z * sB;
    const float* bias = bias0 ? (bias0 + (size_t)blockIdx.z * sBias) : nullptr;

    const int tid = threadIdx.x, w = tid >> 6, lane = tid & 63;
    const int row0 = blockIdx.y * BM, col0 = blockIdx.x * BN;
    const int wr = w / WC, wc = w % WC;
    const int mi = lane & 15, kq = lane >> 4;
    const int lr = lane >> 2, lc = (lane & 3) * 8;

    float4v acc[RT][CT];
    #pragma unroll
    for (int i = 0; i < RT; ++i)
        #pragma unroll
        for (int j = 0; j < CT; ++j) acc[i][j] = (float4v){0.f, 0.f, 0.f, 0.f};

    for (int kk = 0; kk < K; kk += BK) {
        __syncthreads();
        for (int i = w; i < BM / 16; i += 4) {
            const u16* g = A + (size_t)(row0 + i * 16 + lr) * lda + kk + lc;
            __builtin_amdgcn_global_load_lds(
                (const __attribute__((address_space(1))) void*)g,
                (__attribute__((address_space(3))) void*)(As + i * 16 * BK), 16, 0, 0);
        }
        for (int i = w; i < BN / 16; i += 4) {
            const u16* g = Bt + (size_t)(col0 + i * 16 + lr) * ldb + kk + lc;
            __builtin_amdgcn_global_load_lds(
                (const __attribute__((address_space(1))) void*)g,
                (__attribute__((address_space(3))) void*)(Bs + i * 16 * BK), 16, 0, 0);
        }
        __syncthreads();
        short8 af[RT], bf[CT];
        #pragma unroll
        for (int i = 0; i < RT; ++i)
            af[i] = *(const short8*)(As + (wr * RT * 16 + i * 16 + mi) * BK + kq * 8);
        #pragma unroll
        for (int j = 0; j < CT; ++j)
            bf[j] = *(const short8*)(Bs + (wc * CT * 16 + j * 16 + mi) * BK + kq * 8);
        #pragma unroll
        for (int i = 0; i < RT; ++i)
            #pragma unroll
            for (int j = 0; j < CT; ++j)
                acc[i][j] = __builtin_amdgcn_mfma_f32_16x16x32_bf16(af[i], bf[j], acc[i][j], 0, 0, 0);
    }

    #pragma unroll
    for (int j = 0; j < CT; ++j) {
        const int n = col0 + wc * CT * 16 + j * 16 + mi;
        const float bv = bias ? bias[n] : 0.f;
        float s = 0.f, q = 0.f;
        #pragma unroll
        for (int i = 0; i < RT; ++i) {
            #pragma unroll
            for (int r = 0; r < 4; ++r) {
                int m = row0 + wr * RT * 16 + i * 16 + kq * 4 + r;
                float v = acc[i][j][r] + bv;
                if (act == 1) v = fmaxf(v, 0.f);
                if (outfp)
                    ((float*)C0)[(size_t)blockIdx.z * sC + (size_t)m * ldc + n] = v;
                else
                    ((u16*)C0)[(size_t)blockIdx.z * sC + (size_t)m * ldc + n] = f2bf(v);
                s += v; q += v * v;
            }
        }
        if (stats) {
            s += __shfl_xor(s, 16); s += __shfl_xor(s, 32);
            q += __shfl_xor(q, 16); q += __shfl_xor(q, 32);
            if (lane < 16) {
                atomicAdd(&stats[(size_t)(blockIdx.z * statsStride + n) * 2], s);
                atomicAdd(&stats[(size_t)(blockIdx.z * statsStride + n) * 2 + 1], q);
            }
        }
    }
}

// ---- fused: conv+SiLU (16 tok x 512 d in LDS) -> xdb GEMM -> bcT + delta GEMM ------
// grid: 256 blocks = dir(2) x 128 tiles of 16 tokens. 256 threads.
__global__ __launch_bounds__(256) void xcdelta_kernel(
    const u16* __restrict__ xz, const float* __restrict__ conv_w,
    const float* __restrict__ conv_b, const u16* __restrict__ wxT_l,
    const u16* __restrict__ wdtT_l, const float* __restrict__ bdt_l,
    u16* __restrict__ xc, u16* __restrict__ bcT,
    u16* __restrict__ deltaT, u16* __restrict__ uT, int layer)
{
    __shared__ u16 xcs[16 * XCP];    // ~16.6 KB
    __shared__ u16 xdb16[16 * 16];
    const short8 zer = {0, 0, 0, 0, 0, 0, 0, 0};
    int vb = blockIdx.x;
    int dir = vb >> 7, tile = vb & 127;
    int m0 = tile * 16;                 // token index within dir (0..2047)
    int b = m0 >> 10, tbase = m0 & 1023;
    int tid = threadIdx.x;
    int w = tid >> 6, lane = tid & 63;
    int mi = lane & 15, kq = lane >> 4;

    // ---- phase 1: conv + silu into LDS (and global xc for the gate) ----
    for (int e = tid; e < 16 * 512; e += 256) {
        int row = e >> 9, d = e & 511;
        int t = tbase + row;
        int wbase = ((layer * 2 + dir) * DI + d);
        float acc = conv_b[wbase];
        int colbase = dir * 1024 + d;
        #pragma unroll
        for (int k = 0; k < KCONV; ++k) {
            int ts = dir ? (t + 3 - k) : (t - 3 + k);
            if (ts >= 0 && ts < LSEQ)
                acc += conv_w[wbase * KCONV + k] * bf2f(xz[(size_t)((b << 10) + ts) * 2048 + colbase]);
        }
        float v = acc / (1.f + __expf(-acc));
        u16 hv = f2bf(v);
        xcs[row * XCP + d] = hv;
        xc[(size_t)(((dir * 2 + b) << 10) + t) * DI + d] = hv;
    }
    __syncthreads();

    // ---- phase 2: xdb = xcs @ Wx^T (16 x 48); waves 0..2; cols 16..47 -> bcT ----
    if (w < 3) {
        int n = w * 16 + mi;
        const u16* Brow = wxT_l + (size_t)dir * 48 * 512 + (size_t)n * 512;
        float4v acc = (float4v){0.f, 0.f, 0.f, 0.f};
        for (int kk = 0; kk < 512; kk += 32) {
            short8 af = *(const short8*)(xcs + mi * XCP + kk + kq * 8);
            short8 bf = *(const short8*)(Brow + kk + kq * 8);
            acc = __builtin_amdgcn_mfma_f32_16x16x32_bf16(af, bf, acc, 0, 0, 0);
        }
        #pragma unroll
        for (int rr = 0; rr < 4; ++rr) {
            int m = kq * 4 + rr;
            u16 hv = f2bf(acc[rr]);
            if (w == 0) xdb16[m * 16 + mi] = hv;
            else bcT[((size_t)((dir * 2 + b) * 32 + (n - 16))) * 1024 + tbase + m] = hv;
        }
    }
    __syncthreads();

    // ---- phase 3: delta = softplus(xdb16 @ Wdt + bdt), 16 x 512, K=16 ----
    short8 af = (kq < 2) ? *(const short8*)(xdb16 + mi * 16 + kq * 8) : zer;
    const u16* wdtTd = wdtT_l + (size_t)dir * 512 * 16;
    const float* biasd = bdt_l + (size_t)dir * 512;
    #pragma unroll
    for (int ct = 0; ct < 8; ++ct) {
        int n = w * 128 + ct * 16 + mi;
        short8 bf = (kq < 2) ? *(const short8*)(wdtTd + (size_t)n * 16 + kq * 8) : zer;
        float4v acc = __builtin_amdgcn_mfma_f32_16x16x32_bf16(af, bf,
                      (float4v){0.f, 0.f, 0.f, 0.f}, 0, 0, 0);
        #pragma unroll
        for (int rr = 0; rr < 4; ++rr) {
            int m = kq * 4 + rr;
            float v = acc[rr] + biasd[n];
            v = (v > 20.f) ? v : logf(1.f + __expf(v));   // softplus
            float xcv = bf2f(xcs[m * XCP + n]);
            size_t off = ((size_t)((dir * 2 + b) * 512 + n)) * 1024 + tbase + m;
            deltaT[off] = f2bf(v);
            uT[off] = f2bf(v * xcv);
        }
    }
}

// ---------------- embedding ----------------
__global__ __launch_bounds__(256) void embed_kernel(
    const int* __restrict__ ids, const float* __restrict__ emb,
    const float* __restrict__ pos, u16* __restrict__ x)
{
    int tok = blockIdx.x, d = threadIdx.x;
    int id = ids[tok];
    float v = emb[(size_t)id * DMODEL + d] * 16.0f + pos[(size_t)(tok & (LSEQ - 1)) * DMODEL + d];
    x[(size_t)tok * DMODEL + d] = f2bf(v);
}

// ---------------- selective scan: n-outer streaming, coalesced bcT, K-S stitch ----
template<int DIR>
__device__ __forceinline__ void scan_body(
    const u16* __restrict__ deltaT, const u16* __restrict__ uT,
    const u16* __restrict__ bcT, const float* __restrict__ A_log,
    u16* __restrict__ pT, int layer, int slab,
    float* Ps, float* Qs)
{
    const int c = threadIdx.x;   // chunk 0..127
    const int d = blockIdx.x;

    float a2[16];
    const float* al = A_log + (size_t)(((layer * 2 + DIR) * DI + d) * NN);
    #pragma unroll
    for (int n = 0; n < 16; ++n) a2[n] = -__expf(al[n]) * 1.44269504f;

    const size_t tb = ((size_t)(slab * DI + d)) * LSEQ;
    const size_t bcb = (size_t)slab * 32 * LSEQ;
    const int T0 = DIR ? (1016 - 8 * c) : (8 * c);

    short8 dlv = *(const short8*)(deltaT + tb + T0);
    short8 uvv = *(const short8*)(uT + tb + T0);
    float dls[8], uvs[8];
    #pragma unroll
    for (int s = 0; s < 8; ++s) {
        const int idx = DIR ? 7 - s : s;
        dls[s] = bf2f((u16)dlv[idx]);
        uvs[s] = bf2f((u16)uvv[idx]);
    }

    const int base = c * 17;
    #pragma unroll
    for (int n = 0; n < 16; ++n) {
        short8 B8 = *(const short8*)(bcT + bcb + (size_t)n * LSEQ + T0);
        float P = 1.f, Q = 0.f;
        #pragma unroll
        for (int s = 0; s < 8; ++s) {
            const int idx = DIR ? 7 - s : s;
            float dA = EXP2(dls[s] * a2[n]);
            Q = Q * dA + uvs[s] * bf2f((u16)B8[idx]);
            P *= dA;
        }
        Ps[base + n] = P;
        Qs[base + n] = Q;
    }
    __syncthreads();

    for (int off = 1; off < 128; off <<= 1) {
        float np[16], nq[16];
        const bool act = (c >= off);
        if (act) {
            const int nb = (c - off) * 17;
            #pragma unroll
            for (int n = 0; n < 16; ++n) { np[n] = Ps[nb + n]; nq[n] = Qs[nb + n]; }
        }
        __syncthreads();
        if (act) {
            #pragma unroll
            for (int n = 0; n < 16; ++n) {
                float p = Ps[base + n], q = Qs[base + n];
                Qs[base + n] = fmaf(p, nq[n], q);
                Ps[base + n] = p * np[n];
            }
        }
        __syncthreads();
    }

    float pacc[8];
    #pragma unroll
    for (int s = 0; s < 8; ++s) pacc[s] = 0.f;
    const int hb = (c - 1) * 17;
    #pragma unroll
    for (int n = 0; n < 16; ++n) {
        short8 B8 = *(const short8*)(bcT + bcb + (size_t)n * LSEQ + T0);
        short8 C8 = *(const short8*)(bcT + bcb + (size_t)(16 + n) * LSEQ + T0);
        float h = (c == 0) ? 0.f : Qs[hb + n];
        #pragma unroll
        for (int s = 0; s < 8; ++s) {
            const int idx = DIR ? 7 - s : s;
            float dA = EXP2(dls[s] * a2[n]);
            h = h * dA + uvs[s] * bf2f((u16)B8[idx]);
            pacc[s] = fmaf(h, bf2f((u16)C8[idx]), pacc[s]);
        }
    }
    short8 pk;
    #pragma unroll
    for (int s = 0; s < 8; ++s) {
        const int idx = DIR ? 7 - s : s;
        pk[idx] = (short)f2bf(pacc[s]);
    }
    *(short8*)(pT + tb + T0) = pk;
}

__global__ __launch_bounds__(128) void scan_kernel(
    const u16* __restrict__ deltaT, const u16* __restrict__ uT,
    const u16* __restrict__ bcT, const float* __restrict__ A_log,
    u16* __restrict__ pT, int layer)
{
    __shared__ float Ps[128 * 17], Qs[128 * 17];
    int slab = blockIdx.y;
    if (slab >> 1)
        scan_body<1>(deltaT, uT, bcT, A_log, pT, layer, slab, Ps, Qs);
    else
        scan_body<0>(deltaT, uT, bcT, A_log, pT, layer, slab, Ps, Qs);
}

// ---------------- gate: y = (p + Dskip*xc) * silu(z); also zeroes statsM ----------------
__global__ __launch_bounds__(256) void gate_kernel(
    const u16* __restrict__ pT, const u16* __restrict__ xc,
    const u16* __restrict__ xz, const float* __restrict__ Dskip,
    u16* __restrict__ y, float* __restrict__ statsM, int layer)
{
    if (blockIdx.x == 0 && blockIdx.y == 0 && blockIdx.z == 0) {
        for (int k = threadIdx.x; k < 2048; k += 256) statsM[k] = 0.f;
    }
    __shared__ float tile[32][33];
    int z = blockIdx.z, dir = z >> 1, b = z & 1;
    int d0 = blockIdx.x * 32, t0 = blockIdx.y * 32;
    int tx = threadIdx.x & 31, ty = threadIdx.x >> 5;
    #pragma unroll
    for (int k = 0; k < 4; ++k) {
        int d = d0 + ty + k * 8;
        tile[ty + k * 8][tx] = bf2f(pT[((size_t)(z * DI + d)) * LSEQ + t0 + tx]);
    }
    __syncthreads();
    #pragma unroll
    for (int k = 0; k < 4; ++k) {
        int t = t0 + ty + k * 8, d = d0 + tx;
        float p = tile[tx][ty + k * 8];
        float xcv = bf2f(xc[(size_t)((z << 10) + t) * DI + d]);
        float zv = bf2f(xz[(size_t)((b << 10) + t) * 2048 + dir * 1024 + 512 + d]);
        float dsk = Dskip[(layer * 2 + dir) * DI + d];
        float yv = (p + dsk * xcv) * (zv / (1.f + __expf(-zv)));
        y[(size_t)((z << 10) + t) * DI + d] = f2bf(yv);
    }
}

// ------- fused: BN-apply(f,bk from raw sums) + residual + LN both + sum; zero statsF -------
__global__ __launch_bounds__(256) void fuseln_kernel(
    const u16* __restrict__ x, const u16* __restrict__ outm, const float* __restrict__ stats,
    const float* __restrict__ bng, const float* __restrict__ bnb,
    const float* __restrict__ lng, const float* __restrict__ lnb,
    u16* __restrict__ ffin, float* __restrict__ statsF)
{
    int tok = blockIdx.x, d = threadIdx.x;
    if (tok == 0) { for (int k = d; k < 512; k += 256) statsF[k] = 0.f; }
    float xv = bf2f(x[(size_t)tok * DMODEL + d]);
    float of = bf2f(outm[(size_t)tok * DMODEL + d]);
    float ob = bf2f(outm[(size_t)BTOK * DMODEL + (size_t)tok * DMODEL + d]);
    float mf0 = stats[d * 2] * (1.f / 2048.f);
    float rf0 = rsqrtf(stats[d * 2 + 1] * (1.f / 2048.f) - mf0 * mf0 + EPS);
    float mb0 = stats[(DMODEL + d) * 2] * (1.f / 2048.f);
    float rb0 = rsqrtf(stats[(DMODEL + d) * 2 + 1] * (1.f / 2048.f) - mb0 * mb0 + EPS);
    float vf = xv + (of - mf0) * rf0 * bng[d] + bnb[d];
    float vb = xv + (ob - mb0) * rb0 * bng[DMODEL + d] + bnb[DMODEL + d];
    float s0 = vf, s1 = vf * vf, s2 = vb, s3 = vb * vb;
    #pragma unroll
    for (int off = 1; off < 64; off <<= 1) {
        s0 += __shfl_xor(s0, off); s1 += __shfl_xor(s1, off);
        s2 += __shfl_xor(s2, off); s3 += __shfl_xor(s3, off);
    }
    __shared__ float sm[4][4];
    if ((d & 63) == 0) { sm[d >> 6][0] = s0; sm[d >> 6][1] = s1; sm[d >> 6][2] = s2; sm[d >> 6][3] = s3; }
    __syncthreads();
    s0 = sm[0][0] + sm[1][0] + sm[2][0] + sm[3][0];
    s1 = sm[0][1] + sm[1][1] + sm[2][1] + sm[3][1];
    s2 = sm[0][2] + sm[1][2] + sm[2][2] + sm[3][2];
    s3 = sm[0][3] + sm[1][3] + sm[2][3] + sm[3][3];
    float mf = s0 * (1.f / 256.f), vvf = s1 * (1.f / 256.f) - mf * mf;
    float mb = s2 * (1.f / 256.f), vvb = s3 * (1.f / 256.f) - mb * mb;
    float fl = (vf - mf) * rsqrtf(vvf + EPS) * lng[d] + lnb[d];
    float bl = (vb - mb) * rsqrtf(vvb + EPS) * lng[DMODEL + d] + lnb[DMODEL + d];
    ffin[(size_t)tok * DMODEL + d] = f2bf(fl + bl);
}

// ---------------- fused: BN-apply(ff, raw sums) + residual add into x ----------------
__global__ __launch_bounds__(256) void bnadd_kernel(
    u16* __restrict__ x, const u16* __restrict__ ffo, const float* __restrict__ stats,
    const float* __restrict__ g, const float* __restrict__ b)
{
    int tok = blockIdx.x, d = threadIdx.x;
    size_t idx = (size_t)tok * DMODEL + d;
    float mean = stats[d * 2] * (1.f / 2048.f);
    float rs = rsqrtf(stats[d * 2 + 1] * (1.f / 2048.f) - mean * mean + EPS);
    float v = bf2f(x[idx]) + (bf2f(ffo[idx]) - mean) * rs * g[d] + b[d];
    x[idx] = f2bf(v);
}

// ---------------- host ----------------
extern "C" void kernel_launch(void* const* d_in, const int* in_sizes, int n_in,
                              void* d_out, int out_size, void* d_ws, size_t ws_size,
                              hipStream_t stream)
{
    const int*   ids     = (const int*)d_in[0];
    const float* emb     = (const float*)d_in[1];
    const float* pos     = (const float*)d_in[2];
    const float* Win     = (const float*)d_in[3];
    const float* conv_w  = (const float*)d_in[4];
    const float* conv_b  = (const float*)d_in[5];
    const float* Wx      = (const float*)d_in[6];
    const float* Wdt     = (const float*)d_in[7];
    const float* bdt     = (const float*)d_in[8];
    const float* A_log   = (const float*)d_in[9];
    const float* Dskip   = (const float*)d_in[10];
    const float* Wout    = (const float*)d_in[11];
    const float* bout    = (const float*)d_in[12];
    const float* bn_g    = (const float*)d_in[13];
    const float* bn_b    = (const float*)d_in[14];
    const float* ln_g    = (const float*)d_in[15];
    const float* ln_b    = (const float*)d_in[16];
    const float* ff_w1   = (const float*)d_in[17];
    const float* ff_b1   = (const float*)d_in[18];
    const float* ff_w2   = (const float*)d_in[19];
    const float* ff_b2   = (const float*)d_in[20];
    const float* final_w = (const float*)d_in[21];
    const float* final_b = (const float*)d_in[22];

    char* cur = (char*)d_ws;
    auto alloc = [&](size_t elems) {
        u16* p = (u16*)cur;
        cur += ((elems * 2 + 511) / 512) * 512;
        return p;
    };
    // transposed bf16 weights
    u16* winT  = alloc((size_t)NL * 2048 * 256);
    u16* wxT   = alloc((size_t)NL * 2 * 48 * 512);
    u16* wdtT  = alloc((size_t)NL * 2 * 512 * 16);
    u16* woutT = alloc((size_t)NL * 2 * 256 * 512);
    u16* fw1T  = alloc((size_t)NL * 1024 * 256);
    u16* fw2T  = alloc((size_t)NL * 256 * 1024);
    u16* finT  = alloc((size_t)1024 * 256);
    // activations (bf16)
    u16* xbuf   = alloc((size_t)BTOK * DMODEL);
    u16* xz     = alloc((size_t)BTOK * 2048);
    u16* xc     = alloc((size_t)2 * BTOK * DI);
    u16* bcT    = alloc((size_t)4 * 32 * LSEQ);
    u16* deltaT = alloc((size_t)2 * BTOK * DI);
    u16* uT     = alloc((size_t)2 * BTOK * DI);
    u16* pT     = alloc((size_t)2 * BTOK * DI);
    u16* ybuf   = alloc((size_t)2 * BTOK * DI);
    u16* outm   = alloc((size_t)2 * BTOK * DMODEL);
    u16* ffin   = alloc((size_t)BTOK * DMODEL);
    u16* ffh    = alloc((size_t)BTOK * FF);
    u16* ffo    = alloc((size_t)BTOK * DMODEL);
    float* statsM = (float*)alloc(8192);          // 16KB: 1024+256 (sum,sumsq) pairs w/ slack
    float* statsF = statsM + 2048;

    // ---- build transpose table ----
    TTable tt; int nm = 0, tiles = 0;
    auto addT = [&](const float* src, u16* dst, int rows, int cols) {
        int tc = (cols + 31) / 32, tr = (rows + 31) / 32;
        tt.m[nm] = {src, dst, rows, cols, tiles, tc};
        tiles += tc * tr; nm++;
    };
    for (int i = 0; i < NL; ++i) {
        for (int dir = 0; dir < 2; ++dir) {
            addT(Win  + (size_t)(i * 2 + dir) * 256 * 1024, winT  + (size_t)i * 2048 * 256 + (size_t)dir * 1024 * 256, 256, 1024);
            addT(Wx   + (size_t)(i * 2 + dir) * 512 * 48,   wxT   + (size_t)(i * 2 + dir) * 48 * 512,   512, 48);
            addT(Wdt  + (size_t)(i * 2 + dir) * 16 * 512,   wdtT  + (size_t)(i * 2 + dir) * 512 * 16,   16, 512);
            addT(Wout + (size_t)(i * 2 + dir) * 512 * 256,  woutT + (size_t)(i * 2 + dir) * 256 * 512,  512, 256);
        }
        addT(ff_w1 + (size_t)i * 256 * 1024, fw1T + (size_t)i * 1024 * 256, 256, 1024);
        addT(ff_w2 + (size_t)i * 1024 * 256, fw2T + (size_t)i * 256 * 1024, 1024, 256);
    }
    addT(final_w, finT, 256, 1024);
    tt.nmat = nm;
    transpose_kernel<<<tiles, 256, 0, stream>>>(tt);

    embed_kernel<<<BTOK, 256, 0, stream>>>(ids, emb, pos, xbuf);

    for (int i = 0; i < NL; ++i) {
        // xz = x @ [Win_f | Win_b]  -> (BTOK, 2048)   [128x128, grid 256]
        sgemm_kernel<128, 128, 2, 2, 4, 4><<<dim3(16, 16), 256, 0, stream>>>(
            xbuf, 256, 0ULL, winT + (size_t)i * 2048 * 256, 256, 0ULL, nullptr, 0ULL,
            xz, 2048, 0ULL, 256, 0, 0, nullptr, 0);
        // conv + xdb + bcT + delta fused
        xcdelta_kernel<<<256, 256, 0, stream>>>(
            xz, conv_w, conv_b, wxT + (size_t)i * 2 * 48 * 512,
            wdtT + (size_t)i * 2 * 512 * 16, bdt + (size_t)i * 2 * 512,
            xc, bcT, deltaT, uT, i);
        // selective scan -> pT (d,t layout)
        scan_kernel<<<dim3(512, 4), 128, 0, stream>>>(deltaT, uT, bcT, A_log, pT, i);
        // gate (+ zero statsM)
        gate_kernel<<<dim3(DI / 32, LSEQ / 32, 4), 256, 0, stream>>>(pT, xc, xz, Dskip, ybuf, statsM, i);
        // out_m = y @ Wout + bout (batched) [64x64, grid 256] + channel stats atomics
        sgemm_kernel<64, 64, 2, 2, 2, 2><<<dim3(4, 32, 2), 256, 0, stream>>>(
            ybuf, 512, (unsigned long long)((size_t)BTOK * 512),
            woutT + (size_t)i * 2 * 256 * 512, 512, 256ULL * 512,
            bout + (size_t)i * 2 * 256, 256ULL,
            outm, 256, (unsigned long long)((size_t)BTOK * 256), 512, 0, 0, statsM, 256);
        // BN apply + residual + LN both + sum -> ffin (+ zero statsF)
        fuseln_kernel<<<BTOK, 256, 0, stream>>>(xbuf, outm, statsM,
            bn_g + (size_t)i * 3 * 256, bn_b + (size_t)i * 3 * 256,
            ln_g + (size_t)i * 2 * 256, ln_b + (size_t)i * 2 * 256, ffin, statsF);
        // FF1 [128x64, grid 256]
        sgemm_kernel<128, 64, 4, 1, 2, 4><<<dim3(16, 16), 256, 0, stream>>>(
            ffin, 256, 0ULL, fw1T + (size_t)i * 1024 * 256, 256, 0ULL,
            ff_b1 + (size_t)i * 1024, 0ULL, ffh, 1024, 0ULL, 256, 1, 0, nullptr, 0);
        // FF2 [64x64, grid 128] + channel stats atomics
        sgemm_kernel<64, 64, 2, 2, 2, 2><<<dim3(4, 32), 256, 0, stream>>>(
            ffh, 1024, 0ULL, fw2T + (size_t)i * 256 * 1024, 1024, 0ULL,
            ff_b2 + (size_t)i * 256, 0ULL, ffo, 256, 0ULL, 1024, 0, 0, statsF, 0);
        // BN apply + residual
        bnadd_kernel<<<BTOK, 256, 0, stream>>>(xbuf, ffo, statsF,
            bn_g + (size_t)(i * 3 + 2) * 256, bn_b + (size_t)(i * 3 + 2) * 256);
    }
    // final logits = x @ final_w + final_b -> d_out (fp32) [128x64, grid 256]
    sgemm_kernel<128, 64, 4, 1, 2, 4><<<dim3(16, 16), 256, 0, stream>>>(
        xbuf, 256, 0ULL, finT, 256, 0ULL, final_b, 0ULL,
        d_out, 1024, 0ULL, 256, 0, 1, nullptr, 0);
}

// Round 14
// 366.061 us; speedup vs baseline: 3.4537x; 1.0742x over previous
//
#include <hip/hip_runtime.h>

// ---------------- constants (problem shape) ----------------
#define NL 2
#define DMODEL 256
#define DI 512
#define FF 1024
#define LSEQ 1024
#define NN 16
#define KCONV 4
#define BTOK 2048   // B * LSEQ
#define EPS 1e-5f
#define XCP 520     // padded LDS row (1040 B = 16B-aligned, breaks power-of-2 conflicts)

using short8 = __attribute__((ext_vector_type(8))) short;
using float4v = __attribute__((ext_vector_type(4))) float;
typedef unsigned short u16;

__device__ inline float bf2f(u16 u) {
    union { unsigned u; float f; } x; x.u = (unsigned)u << 16; return x.f;
}
__device__ inline u16 f2bf(float f) {
    union { float f; unsigned u; } x; x.f = f;
    unsigned r = x.u + 0x7fffu + ((x.u >> 16) & 1u);
    return (u16)(r >> 16);
}

#if __has_builtin(__builtin_amdgcn_exp2f)
#define EXP2(x) __builtin_amdgcn_exp2f(x)
#else
#define EXP2(x) exp2f(x)
#endif

// ---------------- transpose-all (fp32 weights -> bf16 N-major B^T) ----------------
struct TMat { const float* src; u16* dst; int rows, cols, tile0, tilecols; };
struct TTable { TMat m[24]; int nmat; };

__global__ __launch_bounds__(256) void transpose_kernel(TTable tt) {
    __shared__ u16 tile[32][33];
    int bx = blockIdx.x;
    int j = 0;
    for (int k = 1; k < tt.nmat; ++k) if (bx >= tt.m[k].tile0) j = k;
    TMat mm = tt.m[j];
    int lt = bx - mm.tile0;
    int r0 = (lt / mm.tilecols) * 32, c0 = (lt % mm.tilecols) * 32;
    int tx = threadIdx.x & 31, ty = threadIdx.x >> 5;
    #pragma unroll
    for (int k = 0; k < 4; ++k) {
        int r = r0 + ty + k * 8, c = c0 + tx;
        tile[ty + k * 8][tx] = (r < mm.rows && c < mm.cols) ? f2bf(mm.src[(size_t)r * mm.cols + c]) : (u16)0;
    }
    __syncthreads();
    #pragma unroll
    for (int k = 0; k < 4; ++k) {
        int c = c0 + ty + k * 8, r = r0 + tx;
        if (c < mm.cols && r < mm.rows) mm.dst[(size_t)c * mm.rows + r] = tile[tx][ty + k * 8];
    }
}

// ---------------- LDS-staged MFMA GEMM: C = act(A @ Bt^T + bias) [+ channel stats] ---
template<int BM, int BN, int WR, int WC, int RT, int CT>
__global__ __launch_bounds__(256) void sgemm_kernel(
    const u16* __restrict__ A0, int lda, unsigned long long sA,
    const u16* __restrict__ B0, int ldb, unsigned long long sB,
    const float* __restrict__ bias0, unsigned long long sBias,
    void* __restrict__ C0, int ldc, unsigned long long sC,
    int K, int act, int outfp, float* __restrict__ stats, int statsStride)
{
    constexpr int BK = 32;
    __shared__ u16 As[BM * BK];
    __shared__ u16 Bs[BN * BK];
    const u16* A = A0 + (size_t)blockIdx.z * sA;
    const u16* Bt = B0 + (size_t)blockIdx.z * sB;
    const float* bias = bias0 ? (bias0 + (size_t)blockIdx.z * sBias) : nullptr;

    const int tid = threadIdx.x, w = tid >> 6, lane = tid & 63;
    const int row0 = blockIdx.y * BM, col0 = blockIdx.x * BN;
    const int wr = w / WC, wc = w % WC;
    const int mi = lane & 15, kq = lane >> 4;
    const int lr = lane >> 2, lc = (lane & 3) * 8;

    float4v acc[RT][CT];
    #pragma unroll
    for (int i = 0; i < RT; ++i)
        #pragma unroll
        for (int j = 0; j < CT; ++j) acc[i][j] = (float4v){0.f, 0.f, 0.f, 0.f};

    for (int kk = 0; kk < K; kk += BK) {
        __syncthreads();
        for (int i = w; i < BM / 16; i += 4) {
            const u16* g = A + (size_t)(row0 + i * 16 + lr) * lda + kk + lc;
            __builtin_amdgcn_global_load_lds(
                (const __attribute__((address_space(1))) void*)g,
                (__attribute__((address_space(3))) void*)(As + i * 16 * BK), 16, 0, 0);
        }
        for (int i = w; i < BN / 16; i += 4) {
            const u16* g = Bt + (size_t)(col0 + i * 16 + lr) * ldb + kk + lc;
            __builtin_amdgcn_global_load_lds(
                (const __attribute__((address_space(1))) void*)g,
                (__attribute__((address_space(3))) void*)(Bs + i * 16 * BK), 16, 0, 0);
        }
        __syncthreads();
        short8 af[RT], bf[CT];
        #pragma unroll
        for (int i = 0; i < RT; ++i)
            af[i] = *(const short8*)(As + (wr * RT * 16 + i * 16 + mi) * BK + kq * 8);
        #pragma unroll
        for (int j = 0; j < CT; ++j)
            bf[j] = *(const short8*)(Bs + (wc * CT * 16 + j * 16 + mi) * BK + kq * 8);
        #pragma unroll
        for (int i = 0; i < RT; ++i)
            #pragma unroll
            for (int j = 0; j < CT; ++j)
                acc[i][j] = __builtin_amdgcn_mfma_f32_16x16x32_bf16(af[i], bf[j], acc[i][j], 0, 0, 0);
    }

    #pragma unroll
    for (int j = 0; j < CT; ++j) {
        const int n = col0 + wc * CT * 16 + j * 16 + mi;
        const float bv = bias ? bias[n] : 0.f;
        float s = 0.f, q = 0.f;
        #pragma unroll
        for (int i = 0; i < RT; ++i) {
            #pragma unroll
            for (int r = 0; r < 4; ++r) {
                int m = row0 + wr * RT * 16 + i * 16 + kq * 4 + r;
                float v = acc[i][j][r] + bv;
                if (act == 1) v = fmaxf(v, 0.f);
                if (outfp)
                    ((float*)C0)[(size_t)blockIdx.z * sC + (size_t)m * ldc + n] = v;
                else
                    ((u16*)C0)[(size_t)blockIdx.z * sC + (size_t)m * ldc + n] = f2bf(v);
                s += v; q += v * v;
            }
        }
        if (stats) {
            s += __shfl_xor(s, 16); s += __shfl_xor(s, 32);
            q += __shfl_xor(q, 16); q += __shfl_xor(q, 32);
            if (lane < 16) {
                atomicAdd(&stats[(size_t)(blockIdx.z * statsStride + n) * 2], s);
                atomicAdd(&stats[(size_t)(blockIdx.z * statsStride + n) * 2 + 1], q);
            }
        }
    }
}

// ---- fused: conv+SiLU (vectorized, 16 tok x 512 d in LDS) -> xdb GEMM -> bcT + delta ----
// grid: 256 blocks = dir(2) x 128 tiles of 16 tokens. 512 threads (8 waves).
__global__ __launch_bounds__(512) void xcdelta_kernel(
    const u16* __restrict__ xz, const float* __restrict__ conv_w,
    const float* __restrict__ conv_b, const u16* __restrict__ wxT_l,
    const u16* __restrict__ wdtT_l, const float* __restrict__ bdt_l,
    u16* __restrict__ xc, u16* __restrict__ bcT,
    u16* __restrict__ deltaT, u16* __restrict__ uT, int layer)
{
    __shared__ u16 xcs[16 * XCP];    // ~16.6 KB
    __shared__ u16 xdb16[16 * 16];
    const short8 zer = {0, 0, 0, 0, 0, 0, 0, 0};
    int vb = blockIdx.x;
    int dir = vb >> 7, tile = vb & 127;
    int m0 = tile * 16;                 // token index within dir (0..2047)
    int b = m0 >> 10, tbase = m0 & 1023;
    int tid = threadIdx.x;
    int w = tid >> 6, lane = tid & 63;
    int mi = lane & 15, kq = lane >> 4;

    // ---- phase 1: vectorized conv + silu into LDS (and global xc for the gate) ----
    // 1024 work items: 16 rows x 64 groups of 8 consecutive d; 2 iters over 512 threads.
    #pragma unroll
    for (int it = 0; it < 2; ++it) {
        int e = it * 512 + tid;
        int row = e >> 6, d8 = (e & 63) * 8;
        int t = tbase + row;
        int wbase = (layer * 2 + dir) * DI + d8;
        const float* cw = conv_w + (size_t)wbase * 4;   // 32 consecutive floats
        float acc[8];
        #pragma unroll
        for (int j = 0; j < 8; ++j) acc[j] = conv_b[wbase + j];
        int colbase = dir * 1024 + d8;
        #pragma unroll
        for (int k = 0; k < KCONV; ++k) {
            int ts = dir ? (t + 3 - k) : (t - 3 + k);
            if (ts >= 0 && ts < LSEQ) {
                short8 x8 = *(const short8*)(xz + (size_t)((b << 10) + ts) * 2048 + colbase);
                #pragma unroll
                for (int j = 0; j < 8; ++j)
                    acc[j] += cw[j * 4 + k] * bf2f((u16)x8[j]);
            }
        }
        short8 o;
        #pragma unroll
        for (int j = 0; j < 8; ++j) {
            float v = acc[j] / (1.f + __expf(-acc[j]));
            o[j] = (short)f2bf(v);
        }
        *(short8*)(xcs + row * XCP + d8) = o;
        *(short8*)(xc + (size_t)(((dir * 2 + b) << 10) + t) * DI + d8) = o;
    }
    __syncthreads();

    // ---- phase 2: xdb = xcs @ Wx^T (16 x 48); waves 0..2; cols 16..47 -> bcT ----
    if (w < 3) {
        int n = w * 16 + mi;
        const u16* Brow = wxT_l + (size_t)dir * 48 * 512 + (size_t)n * 512;
        float4v acc = (float4v){0.f, 0.f, 0.f, 0.f};
        for (int kk = 0; kk < 512; kk += 32) {
            short8 af = *(const short8*)(xcs + mi * XCP + kk + kq * 8);
            short8 bf = *(const short8*)(Brow + kk + kq * 8);
            acc = __builtin_amdgcn_mfma_f32_16x16x32_bf16(af, bf, acc, 0, 0, 0);
        }
        #pragma unroll
        for (int rr = 0; rr < 4; ++rr) {
            int m = kq * 4 + rr;
            u16 hv = f2bf(acc[rr]);
            if (w == 0) xdb16[m * 16 + mi] = hv;
            else bcT[((size_t)((dir * 2 + b) * 32 + (n - 16))) * 1024 + tbase + m] = hv;
        }
    }
    __syncthreads();

    // ---- phase 3: delta = softplus(xdb16 @ Wdt + bdt), 16 x 512, K=16; 8 waves x 4 ----
    short8 af = (kq < 2) ? *(const short8*)(xdb16 + mi * 16 + kq * 8) : zer;
    const u16* wdtTd = wdtT_l + (size_t)dir * 512 * 16;
    const float* biasd = bdt_l + (size_t)dir * 512;
    #pragma unroll
    for (int ct = 0; ct < 4; ++ct) {
        int n = w * 64 + ct * 16 + mi;
        short8 bf = (kq < 2) ? *(const short8*)(wdtTd + (size_t)n * 16 + kq * 8) : zer;
        float4v acc = __builtin_amdgcn_mfma_f32_16x16x32_bf16(af, bf,
                      (float4v){0.f, 0.f, 0.f, 0.f}, 0, 0, 0);
        #pragma unroll
        for (int rr = 0; rr < 4; ++rr) {
            int m = kq * 4 + rr;
            float v = acc[rr] + biasd[n];
            v = (v > 20.f) ? v : logf(1.f + __expf(v));   // softplus
            float xcv = bf2f(xcs[m * XCP + n]);
            size_t off = ((size_t)((dir * 2 + b) * 512 + n)) * 1024 + tbase + m;
            deltaT[off] = f2bf(v);
            uT[off] = f2bf(v * xcv);
        }
    }
}

// ---------------- embedding ----------------
__global__ __launch_bounds__(256) void embed_kernel(
    const int* __restrict__ ids, const float* __restrict__ emb,
    const float* __restrict__ pos, u16* __restrict__ x)
{
    int tok = blockIdx.x, d = threadIdx.x;
    int id = ids[tok];
    float v = emb[(size_t)id * DMODEL + d] * 16.0f + pos[(size_t)(tok & (LSEQ - 1)) * DMODEL + d];
    x[(size_t)tok * DMODEL + d] = f2bf(v);
}

// ---------------- selective scan: n-outer streaming, coalesced bcT, K-S stitch ----
template<int DIR>
__device__ __forceinline__ void scan_body(
    const u16* __restrict__ deltaT, const u16* __restrict__ uT,
    const u16* __restrict__ bcT, const float* __restrict__ A_log,
    u16* __restrict__ pT, int layer, int slab,
    float* Ps, float* Qs)
{
    const int c = threadIdx.x;   // chunk 0..127
    const int d = blockIdx.x;

    float a2[16];
    const float* al = A_log + (size_t)(((layer * 2 + DIR) * DI + d) * NN);
    #pragma unroll
    for (int n = 0; n < 16; ++n) a2[n] = -__expf(al[n]) * 1.44269504f;

    const size_t tb = ((size_t)(slab * DI + d)) * LSEQ;
    const size_t bcb = (size_t)slab * 32 * LSEQ;
    const int T0 = DIR ? (1016 - 8 * c) : (8 * c);

    short8 dlv = *(const short8*)(deltaT + tb + T0);
    short8 uvv = *(const short8*)(uT + tb + T0);
    float dls[8], uvs[8];
    #pragma unroll
    for (int s = 0; s < 8; ++s) {
        const int idx = DIR ? 7 - s : s;
        dls[s] = bf2f((u16)dlv[idx]);
        uvs[s] = bf2f((u16)uvv[idx]);
    }

    const int base = c * 17;
    #pragma unroll
    for (int n = 0; n < 16; ++n) {
        short8 B8 = *(const short8*)(bcT + bcb + (size_t)n * LSEQ + T0);
        float P = 1.f, Q = 0.f;
        #pragma unroll
        for (int s = 0; s < 8; ++s) {
            const int idx = DIR ? 7 - s : s;
            float dA = EXP2(dls[s] * a2[n]);
            Q = Q * dA + uvs[s] * bf2f((u16)B8[idx]);
            P *= dA;
        }
        Ps[base + n] = P;
        Qs[base + n] = Q;
    }
    __syncthreads();

    for (int off = 1; off < 128; off <<= 1) {
        float np[16], nq[16];
        const bool act = (c >= off);
        if (act) {
            const int nb = (c - off) * 17;
            #pragma unroll
            for (int n = 0; n < 16; ++n) { np[n] = Ps[nb + n]; nq[n] = Qs[nb + n]; }
        }
        __syncthreads();
        if (act) {
            #pragma unroll
            for (int n = 0; n < 16; ++n) {
                float p = Ps[base + n], q = Qs[base + n];
                Qs[base + n] = fmaf(p, nq[n], q);
                Ps[base + n] = p * np[n];
            }
        }
        __syncthreads();
    }

    float pacc[8];
    #pragma unroll
    for (int s = 0; s < 8; ++s) pacc[s] = 0.f;
    const int hb = (c - 1) * 17;
    #pragma unroll
    for (int n = 0; n < 16; ++n) {
        short8 B8 = *(const short8*)(bcT + bcb + (size_t)n * LSEQ + T0);
        short8 C8 = *(const short8*)(bcT + bcb + (size_t)(16 + n) * LSEQ + T0);
        float h = (c == 0) ? 0.f : Qs[hb + n];
        #pragma unroll
        for (int s = 0; s < 8; ++s) {
            const int idx = DIR ? 7 - s : s;
            float dA = EXP2(dls[s] * a2[n]);
            h = h * dA + uvs[s] * bf2f((u16)B8[idx]);
            pacc[s] = fmaf(h, bf2f((u16)C8[idx]), pacc[s]);
        }
    }
    short8 pk;
    #pragma unroll
    for (int s = 0; s < 8; ++s) {
        const int idx = DIR ? 7 - s : s;
        pk[idx] = (short)f2bf(pacc[s]);
    }
    *(short8*)(pT + tb + T0) = pk;
}

__global__ __launch_bounds__(128) void scan_kernel(
    const u16* __restrict__ deltaT, const u16* __restrict__ uT,
    const u16* __restrict__ bcT, const float* __restrict__ A_log,
    u16* __restrict__ pT, int layer)
{
    __shared__ float Ps[128 * 17], Qs[128 * 17];
    int slab = blockIdx.y;
    if (slab >> 1)
        scan_body<1>(deltaT, uT, bcT, A_log, pT, layer, slab, Ps, Qs);
    else
        scan_body<0>(deltaT, uT, bcT, A_log, pT, layer, slab, Ps, Qs);
}

// ---------------- gate: y = (p + Dskip*xc) * silu(z); also zeroes statsM ----------------
__global__ __launch_bounds__(256) void gate_kernel(
    const u16* __restrict__ pT, const u16* __restrict__ xc,
    const u16* __restrict__ xz, const float* __restrict__ Dskip,
    u16* __restrict__ y, float* __restrict__ statsM, int layer)
{
    if (blockIdx.x == 0 && blockIdx.y == 0 && blockIdx.z == 0) {
        for (int k = threadIdx.x; k < 2048; k += 256) statsM[k] = 0.f;
    }
    __shared__ float tile[32][33];
    int z = blockIdx.z, dir = z >> 1, b = z & 1;
    int d0 = blockIdx.x * 32, t0 = blockIdx.y * 32;
    int tx = threadIdx.x & 31, ty = threadIdx.x >> 5;
    #pragma unroll
    for (int k = 0; k < 4; ++k) {
        int d = d0 + ty + k * 8;
        tile[ty + k * 8][tx] = bf2f(pT[((size_t)(z * DI + d)) * LSEQ + t0 + tx]);
    }
    __syncthreads();
    #pragma unroll
    for (int k = 0; k < 4; ++k) {
        int t = t0 + ty + k * 8, d = d0 + tx;
        float p = tile[tx][ty + k * 8];
        float xcv = bf2f(xc[(size_t)((z << 10) + t) * DI + d]);
        float zv = bf2f(xz[(size_t)((b << 10) + t) * 2048 + dir * 1024 + 512 + d]);
        float dsk = Dskip[(layer * 2 + dir) * DI + d];
        float yv = (p + dsk * xcv) * (zv / (1.f + __expf(-zv)));
        y[(size_t)((z << 10) + t) * DI + d] = f2bf(yv);
    }
}

// ------- fused: BN-apply(f,bk from raw sums) + residual + LN both + sum; zero statsF -------
__global__ __launch_bounds__(256) void fuseln_kernel(
    const u16* __restrict__ x, const u16* __restrict__ outm, const float* __restrict__ stats,
    const float* __restrict__ bng, const float* __restrict__ bnb,
    const float* __restrict__ lng, const float* __restrict__ lnb,
    u16* __restrict__ ffin, float* __restrict__ statsF)
{
    int tok = blockIdx.x, d = threadIdx.x;
    if (tok == 0) { for (int k = d; k < 512; k += 256) statsF[k] = 0.f; }
    float xv = bf2f(x[(size_t)tok * DMODEL + d]);
    float of = bf2f(outm[(size_t)tok * DMODEL + d]);
    float ob = bf2f(outm[(size_t)BTOK * DMODEL + (size_t)tok * DMODEL + d]);
    float mf0 = stats[d * 2] * (1.f / 2048.f);
    float rf0 = rsqrtf(stats[d * 2 + 1] * (1.f / 2048.f) - mf0 * mf0 + EPS);
    float mb0 = stats[(DMODEL + d) * 2] * (1.f / 2048.f);
    float rb0 = rsqrtf(stats[(DMODEL + d) * 2 + 1] * (1.f / 2048.f) - mb0 * mb0 + EPS);
    float vf = xv + (of - mf0) * rf0 * bng[d] + bnb[d];
    float vb = xv + (ob - mb0) * rb0 * bng[DMODEL + d] + bnb[DMODEL + d];
    float s0 = vf, s1 = vf * vf, s2 = vb, s3 = vb * vb;
    #pragma unroll
    for (int off = 1; off < 64; off <<= 1) {
        s0 += __shfl_xor(s0, off); s1 += __shfl_xor(s1, off);
        s2 += __shfl_xor(s2, off); s3 += __shfl_xor(s3, off);
    }
    __shared__ float sm[4][4];
    if ((d & 63) == 0) { sm[d >> 6][0] = s0; sm[d >> 6][1] = s1; sm[d >> 6][2] = s2; sm[d >> 6][3] = s3; }
    __syncthreads();
    s0 = sm[0][0] + sm[1][0] + sm[2][0] + sm[3][0];
    s1 = sm[0][1] + sm[1][1] + sm[2][1] + sm[3][1];
    s2 = sm[0][2] + sm[1][2] + sm[2][2] + sm[3][2];
    s3 = sm[0][3] + sm[1][3] + sm[2][3] + sm[3][3];
    float mf = s0 * (1.f / 256.f), vvf = s1 * (1.f / 256.f) - mf * mf;
    float mb = s2 * (1.f / 256.f), vvb = s3 * (1.f / 256.f) - mb * mb;
    float fl = (vf - mf) * rsqrtf(vvf + EPS) * lng[d] + lnb[d];
    float bl = (vb - mb) * rsqrtf(vvb + EPS) * lng[DMODEL + d] + lnb[DMODEL + d];
    ffin[(size_t)tok * DMODEL + d] = f2bf(fl + bl);
}

// ---------------- fused: BN-apply(ff, raw sums) + residual add into x ----------------
__global__ __launch_bounds__(256) void bnadd_kernel(
    u16* __restrict__ x, const u16* __restrict__ ffo, const float* __restrict__ stats,
    const float* __restrict__ g, const float* __restrict__ b)
{
    int tok = blockIdx.x, d = threadIdx.x;
    size_t idx = (size_t)tok * DMODEL + d;
    float mean = stats[d * 2] * (1.f / 2048.f);
    float rs = rsqrtf(stats[d * 2 + 1] * (1.f / 2048.f) - mean * mean + EPS);
    float v = bf2f(x[idx]) + (bf2f(ffo[idx]) - mean) * rs * g[d] + b[d];
    x[idx] = f2bf(v);
}

// ---------------- host ----------------
extern "C" void kernel_launch(void* const* d_in, const int* in_sizes, int n_in,
                              void* d_out, int out_size, void* d_ws, size_t ws_size,
                              hipStream_t stream)
{
    const int*   ids     = (const int*)d_in[0];
    const float* emb     = (const float*)d_in[1];
    const float* pos     = (const float*)d_in[2];
    const float* Win     = (const float*)d_in[3];
    const float* conv_w  = (const float*)d_in[4];
    const float* conv_b  = (const float*)d_in[5];
    const float* Wx      = (const float*)d_in[6];
    const float* Wdt     = (const float*)d_in[7];
    const float* bdt     = (const float*)d_in[8];
    const float* A_log   = (const float*)d_in[9];
    const float* Dskip   = (const float*)d_in[10];
    const float* Wout    = (const float*)d_in[11];
    const float* bout    = (const float*)d_in[12];
    const float* bn_g    = (const float*)d_in[13];
    const float* bn_b    = (const float*)d_in[14];
    const float* ln_g    = (const float*)d_in[15];
    const float* ln_b    = (const float*)d_in[16];
    const float* ff_w1   = (const float*)d_in[17];
    const float* ff_b1   = (const float*)d_in[18];
    const float* ff_w2   = (const float*)d_in[19];
    const float* ff_b2   = (const float*)d_in[20];
    const float* final_w = (const float*)d_in[21];
    const float* final_b = (const float*)d_in[22];

    char* cur = (char*)d_ws;
    auto alloc = [&](size_t elems) {
        u16* p = (u16*)cur;
        cur += ((elems * 2 + 511) / 512) * 512;
        return p;
    };
    // transposed bf16 weights
    u16* winT  = alloc((size_t)NL * 2048 * 256);
    u16* wxT   = alloc((size_t)NL * 2 * 48 * 512);
    u16* wdtT  = alloc((size_t)NL * 2 * 512 * 16);
    u16* woutT = alloc((size_t)NL * 2 * 256 * 512);
    u16* fw1T  = alloc((size_t)NL * 1024 * 256);
    u16* fw2T  = alloc((size_t)NL * 256 * 1024);
    u16* finT  = alloc((size_t)1024 * 256);
    // activations (bf16)
    u16* xbuf   = alloc((size_t)BTOK * DMODEL);
    u16* xz     = alloc((size_t)BTOK * 2048);
    u16* xc     = alloc((size_t)2 * BTOK * DI);
    u16* bcT    = alloc((size_t)4 * 32 * LSEQ);
    u16* deltaT = alloc((size_t)2 * BTOK * DI);
    u16* uT     = alloc((size_t)2 * BTOK * DI);
    u16* pT     = alloc((size_t)2 * BTOK * DI);
    u16* ybuf   = alloc((size_t)2 * BTOK * DI);
    u16* outm   = alloc((size_t)2 * BTOK * DMODEL);
    u16* ffin   = alloc((size_t)BTOK * DMODEL);
    u16* ffh    = alloc((size_t)BTOK * FF);
    u16* ffo    = alloc((size_t)BTOK * DMODEL);
    float* statsM = (float*)alloc(8192);          // 16KB: 1024+256 (sum,sumsq) pairs w/ slack
    float* statsF = statsM + 2048;

    // ---- build transpose table ----
    TTable tt; int nm = 0, tiles = 0;
    auto addT = [&](const float* src, u16* dst, int rows, int cols) {
        int tc = (cols + 31) / 32, tr = (rows + 31) / 32;
        tt.m[nm] = {src, dst, rows, cols, tiles, tc};
        tiles += tc * tr; nm++;
    };
    for (int i = 0; i < NL; ++i) {
        for (int dir = 0; dir < 2; ++dir) {
            addT(Win  + (size_t)(i * 2 + dir) * 256 * 1024, winT  + (size_t)i * 2048 * 256 + (size_t)dir * 1024 * 256, 256, 1024);
            addT(Wx   + (size_t)(i * 2 + dir) * 512 * 48,   wxT   + (size_t)(i * 2 + dir) * 48 * 512,   512, 48);
            addT(Wdt  + (size_t)(i * 2 + dir) * 16 * 512,   wdtT  + (size_t)(i * 2 + dir) * 512 * 16,   16, 512);
            addT(Wout + (size_t)(i * 2 + dir) * 512 * 256,  woutT + (size_t)(i * 2 + dir) * 256 * 512,  512, 256);
        }
        addT(ff_w1 + (size_t)i * 256 * 1024, fw1T + (size_t)i * 1024 * 256, 256, 1024);
        addT(ff_w2 + (size_t)i * 1024 * 256, fw2T + (size_t)i * 256 * 1024, 1024, 256);
    }
    addT(final_w, finT, 256, 1024);
    tt.nmat = nm;
    transpose_kernel<<<tiles, 256, 0, stream>>>(tt);

    embed_kernel<<<BTOK, 256, 0, stream>>>(ids, emb, pos, xbuf);

    for (int i = 0; i < NL; ++i) {
        // xz = x @ [Win_f | Win_b]  -> (BTOK, 2048)   [128x128, grid 256]
        sgemm_kernel<128, 128, 2, 2, 4, 4><<<dim3(16, 16), 256, 0, stream>>>(
            xbuf, 256, 0ULL, winT + (size_t)i * 2048 * 256, 256, 0ULL, nullptr, 0ULL,
            xz, 2048, 0ULL, 256, 0, 0, nullptr, 0);
        // conv + xdb + bcT + delta fused (512 threads, vectorized conv)
        xcdelta_kernel<<<256, 512, 0, stream>>>(
            xz, conv_w, conv_b, wxT + (size_t)i * 2 * 48 * 512,
            wdtT + (size_t)i * 2 * 512 * 16, bdt + (size_t)i * 2 * 512,
            xc, bcT, deltaT, uT, i);
        // selective scan -> pT (d,t layout)
        scan_kernel<<<dim3(512, 4), 128, 0, stream>>>(deltaT, uT, bcT, A_log, pT, i);
        // gate (+ zero statsM)
        gate_kernel<<<dim3(DI / 32, LSEQ / 32, 4), 256, 0, stream>>>(pT, xc, xz, Dskip, ybuf, statsM, i);
        // out_m = y @ Wout + bout (batched) [64x64, grid 256] + channel stats atomics
        sgemm_kernel<64, 64, 2, 2, 2, 2><<<dim3(4, 32, 2), 256, 0, stream>>>(
            ybuf, 512, (unsigned long long)((size_t)BTOK * 512),
            woutT + (size_t)i * 2 * 256 * 512, 512, 256ULL * 512,
            bout + (size_t)i * 2 * 256, 256ULL,
            outm, 256, (unsigned long long)((size_t)BTOK * 256), 512, 0, 0, statsM, 256);
        // BN apply + residual + LN both + sum -> ffin (+ zero statsF)
        fuseln_kernel<<<BTOK, 256, 0, stream>>>(xbuf, outm, statsM,
            bn_g + (size_t)i * 3 * 256, bn_b + (size_t)i * 3 * 256,
            ln_g + (size_t)i * 2 * 256, ln_b + (size_t)i * 2 * 256, ffin, statsF);
        // FF1 [128x64, grid 256]
        sgemm_kernel<128, 64, 4, 1, 2, 4><<<dim3(16, 16), 256, 0, stream>>>(
            ffin, 256, 0ULL, fw1T + (size_t)i * 1024 * 256, 256, 0ULL,
            ff_b1 + (size_t)i * 1024, 0ULL, ffh, 1024, 0ULL, 256, 1, 0, nullptr, 0);
        // FF2 [64x64, grid 128] + channel stats atomics
        sgemm_kernel<64, 64, 2, 2, 2, 2><<<dim3(4, 32), 256, 0, stream>>>(
            ffh, 1024, 0ULL, fw2T + (size_t)i * 256 * 1024, 1024, 0ULL,
            ff_b2 + (size_t)i * 256, 0ULL, ffo, 256, 0ULL, 1024, 0, 0, statsF, 0);
        // BN apply + residual
        bnadd_kernel<<<BTOK, 256, 0, stream>>>(xbuf, ffo, statsF,
            bn_g + (size_t)(i * 3 + 2) * 256, bn_b + (size_t)(i * 3 + 2) * 256);
    }
    // final logits = x @ final_w + final_b -> d_out (fp32) [128x64, grid 256]
    sgemm_kernel<128, 64, 4, 1, 2, 4><<<dim3(16, 16), 256, 0, stream>>>(
        xbuf, 256, 0ULL, finT, 256, 0ULL, final_b, 0ULL,
        d_out, 1024, 0ULL, 256, 0, 1, nullptr, 0);
}